// Round 9
// baseline (195.185 us; speedup 1.0000x reference)
//
#include <hip/hip_runtime.h>
#include <math.h>

#define L    2048
#define NCOL 4096
#define NG   1024
#define N3   3072
#define T    512
#define NW   8            // waves per block
#define EPT  8            // NCOL / T
#define NB   2048         // buckets (exact: floor(x*2048), power-of-two mult)
#define FEPS 1.1920929e-07f

typedef unsigned long long u64;
typedef unsigned short u16;
typedef unsigned int u32;

__device__ __forceinline__ int lower_bound_f(const float* a, int lo, int hi, float v) {
  // exact replica of numpy's npy_binsearch (side='left') on [lo,hi)
  while (lo < hi) {
    int mid = (lo + hi) >> 1;
    if (a[mid] < v) lo = mid + 1; else hi = mid;
  }
  return lo;
}

__device__ __forceinline__ int bucket_of_bits(unsigned xb) {
  float f = __uint_as_float(xb);
  int b = (int)(f * (float)NB);          // exact: mult by 2^11
  return b > NB - 1 ? NB - 1 : b;
}

__device__ __forceinline__ float vgrid(int m) {   // LUT grid value, monotone in m
  return -1.0f + 3.0f * (float)m * (1.0f / 256.0f);
}

// LDS layout (37,904 B dynamic -> 4 blocks/CU, 32 waves/CU):
//   [0,32768)      pairs u64[4096]; aliased later: xs f32[4096] @0, ys f32[4096] @16384
//   [16384,28672)  ecdf f32[3072] overlays ys AFTER stage-1 (ys dead by then)
//   [32768,36872)  cnt u16[2050] (packed u32 words for atomics), padded
//   [36872,37386)  lut2 u16[257]
//   [37388,37904)  hist u16[258] (packed u32 words for atomics)
__global__ __launch_bounds__(T, 8) void lcot_rows(const float* __restrict__ X,
                                                  const float* __restrict__ W,
                                                  float* __restrict__ rowsum) {
  extern __shared__ char smem[];
  u64*   pairs = (u64*)smem;
  float* xs    = (float*)smem;
  float* ys    = (float*)(smem + 16384);
  float* ecdf  = (float*)(smem + 16384);          // overlay, used after stage-1
  u16*   cnt16 = (u16*)(smem + 32768);
  u32*   cntw  = (u32*)(smem + 32768);
  u16*   lut2  = (u16*)(smem + 36872);
  u16*   hist  = (u16*)(smem + 37388);
  u32*   histw = (u32*)(smem + 37388);

  __shared__ float redA[NW], redB[NW], fwt[NW];
  __shared__ int   iwt[NW];
  __shared__ float s_alpha;

  const int tid  = threadIdx.x;
  const int lane = tid & 63;
  const int wave = tid >> 6;
  const int row  = blockIdx.x;
  const float* xr = X + (size_t)row * NCOL;
  const float* wr = W + (size_t)row * NCOL;

  // ---- zero packed histogram (1025 u32 words incl. sentinel word) ----
  for (int i = tid; i < 1025; i += T) cntw[i] = 0u;

  // ---- load 8 consecutive elems, pack stable keys, alpha partials ----
  u64 key[EPT];
  float sxw = 0.f, sw = 0.f;
  const float4* xr4 = (const float4*)xr;
  const float4* wr4 = (const float4*)wr;
#pragma unroll
  for (int c = 0; c < 2; ++c) {
    float4 xv = xr4[tid * 2 + c];
    float4 ww = wr4[tid * 2 + c];
    sxw += xv.x * ww.x + xv.y * ww.y + xv.z * ww.z + xv.w * ww.w;
    sw  += ww.x + ww.y + ww.z + ww.w;
    int b = 8 * tid + 4 * c;
    key[4*c+0] = ((u64)__float_as_uint(xv.x) << 32) | (unsigned)(b + 0);
    key[4*c+1] = ((u64)__float_as_uint(xv.y) << 32) | (unsigned)(b + 1);
    key[4*c+2] = ((u64)__float_as_uint(xv.z) << 32) | (unsigned)(b + 2);
    key[4*c+3] = ((u64)__float_as_uint(xv.w) << 32) | (unsigned)(b + 3);
  }
#pragma unroll
  for (int off = 32; off > 0; off >>= 1) {
    sxw += __shfl_down(sxw, off);
    sw  += __shfl_down(sw, off);
  }
  if (lane == 0) { redA[wave] = sxw; redB[wave] = sw; }
  __syncthreads();   // [1] zeroed cnt + redA/redB visible

  // ---- histogram on packed u16 fields: ord from atomic return ----
  int ord[EPT];
#pragma unroll
  for (int e = 0; e < EPT; ++e) {
    int b = bucket_of_bits((unsigned)(key[e] >> 32));
    u32 inc = (b & 1) ? 65536u : 1u;
    u32 ret = atomicAdd(&cntw[b >> 1], inc);
    ord[e] = (b & 1) ? (int)(ret >> 16) : (int)(ret & 0xffffu);
  }
  __syncthreads();   // [2] all atomics done
  if (tid == 0) {
    float a = 0.f, b = 0.f;
#pragma unroll
    for (int i = 0; i < NW; ++i) { a += redA[i]; b += redB[i]; }
    s_alpha = a / b - 0.5f;
  }

  // ---- exclusive scan of 2048 u16 counts -> bases (packed, in place) ----
  u32 cv0 = cntw[2 * tid], cv1 = cntw[2 * tid + 1];
  int c0 = (int)(cv0 & 0xffffu), c1 = (int)(cv0 >> 16);
  int c2 = (int)(cv1 & 0xffffu), c3 = (int)(cv1 >> 16);
  int runi = c0 + c1 + c2 + c3;
  int toti = runi, prei = runi;
#pragma unroll
  for (int off = 1; off < 64; off <<= 1) {
    int v = __shfl_up(prei, off);
    if (lane >= off) prei += v;
  }
  if (lane == 63) iwt[wave] = prei;
  __syncthreads();   // [3] iwt visible (each thread only rewrites its own words)
  int wpre = 0;
#pragma unroll
  for (int w2 = 0; w2 < NW; ++w2) wpre += (w2 < wave) ? iwt[w2] : 0;
  int acc = wpre + prei - toti;
  {
    int b0 = acc; acc += c0;
    int b1 = acc; acc += c1;
    int b2 = acc; acc += c2;
    int b3 = acc; acc += c3;
    cntw[2 * tid]     = (u32)b0 | ((u32)b1 << 16);
    cntw[2 * tid + 1] = (u32)b2 | ((u32)b3 << 16);
  }
  if (tid == T - 1) cnt16[NB] = (u16)acc;   // sentinel = 4096
  __syncthreads();   // [4] bases visible

  // ---- scatter keys into bucket slots (arrival order) ----
#pragma unroll
  for (int e = 0; e < EPT; ++e) {
    int b = bucket_of_bits((unsigned)(key[e] >> 32));
    pairs[(int)cnt16[b] + ord[e]] = key[e];
  }
  __syncthreads();   // [5]

  // ---- per-bucket insertion sort in LDS (4 buckets/thread, disjoint slots) ----
#pragma unroll
  for (int bb = 0; bb < 4; ++bb) {
    int b  = 4 * tid + bb;
    int lo = (int)cnt16[b], hi = (int)cnt16[b + 1];
    for (int i = lo + 1; i < hi; ++i) {
      u64 v = pairs[i];
      int j = i - 1;
      while (j >= lo && pairs[j] > v) { pairs[j + 1] = pairs[j]; --j; }
      pairs[j + 1] = v;
    }
  }
  __syncthreads();   // [6] pairs fully sorted

  // ---- stage own 8 sorted slots to registers; gather w by index ----
  u64 q[EPT];
  {
    const ulonglong2* pr2 = (const ulonglong2*)pairs + 4 * tid;
#pragma unroll
    for (int c = 0; c < 4; ++c) { ulonglong2 v = pr2[c]; q[2*c] = v.x; q[2*c+1] = v.y; }
  }
  float wg[EPT];
#pragma unroll
  for (int e = 0; e < EPT; ++e) wg[e] = wr[(u32)(q[e] & 0xffffffffu)];
  __syncthreads();   // [7] all pairs reads done before aliasing xs/ys writes

  // ---- write sorted xs (vector); cumsum weights in registers ----
  {
    float4 xa0, xa1;
    xa0.x = __uint_as_float((u32)(q[0] >> 32));
    xa0.y = __uint_as_float((u32)(q[1] >> 32));
    xa0.z = __uint_as_float((u32)(q[2] >> 32));
    xa0.w = __uint_as_float((u32)(q[3] >> 32));
    xa1.x = __uint_as_float((u32)(q[4] >> 32));
    xa1.y = __uint_as_float((u32)(q[5] >> 32));
    xa1.z = __uint_as_float((u32)(q[6] >> 32));
    xa1.w = __uint_as_float((u32)(q[7] >> 32));
    ((float4*)xs)[2 * tid]     = xa0;
    ((float4*)xs)[2 * tid + 1] = xa1;
  }
  float lw[EPT];
  float runf = 0.f;
#pragma unroll
  for (int c = 0; c < EPT; ++c) { runf += wg[c]; lw[c] = runf; }
  float totf = runf, pref = runf;
#pragma unroll
  for (int off = 1; off < 64; off <<= 1) {
    float v = __shfl_up(pref, off);
    if (lane >= off) pref += v;
  }
  if (lane == 63) fwt[wave] = pref;
  __syncthreads();   // [8] fwt visible
  float wpf = 0.f;
#pragma unroll
  for (int w2 = 0; w2 < NW; ++w2) wpf += (w2 < wave) ? fwt[w2] : 0.f;
  float basef = wpf + pref - totf;
  {
    ((float4*)ys)[2 * tid]     = make_float4(basef + lw[0], basef + lw[1],
                                             basef + lw[2], basef + lw[3]);
    ((float4*)ys)[2 * tid + 1] = make_float4(basef + lw[4], basef + lw[5],
                                             basef + lw[6], basef + lw[7]);
  }
  if (tid < 129) histw[tid] = 0u;   // zero stage-2 value-histogram (258 u16)
  __syncthreads();   // [9] xs + CDF + zeroed hist visible

  // ---- stage 1: ecdf values into REGISTERS + value-histogram atomics ----
  float ev[N3 / T];
#pragma unroll
  for (int s = 0; s < N3 / T; ++s) {
    int j = tid + s * T;
    float xnew = -1.0f + (3.0f * (float)j) / 3071.0f;
    float ix = floorf(xnew);
    float rest = xnew - ix;                  // in [0,1)
    int k = (int)(rest * (float)NB);         // exact
    k = k > NB - 1 ? NB - 1 : k;
    int lo = lower_bound_f(xs, (int)cnt16[k], (int)cnt16[k + 1], rest);
    int ind = lo - 1;
    ind = ind < 0 ? 0 : (ind > NCOL - 2 ? NCOL - 2 : ind);
    float x0 = xs[ind], x1v = xs[ind + 1];
    float y0 = ys[ind], y1v = ys[ind + 1];
    float slope = (y1v - y0) * __builtin_amdgcn_rcpf(FEPS + (x1v - x0));
    float e = ix + (y0 + slope * (rest - x0));
    ev[s] = e;
    // g(e) = #{m in [0,257): vgrid(m) <= e}, exact via +-1 fp adjust
    int mc = (int)floorf((e + 1.0f) * (256.0f / 3.0f));
    mc = mc < -1 ? -1 : (mc > 256 ? 256 : mc);
    while (mc < 256 && vgrid(mc + 1) <= e) ++mc;
    while (mc >= 0 && vgrid(mc) > e) --mc;
    int g = mc + 1;                          // in [0, 257]
    atomicAdd(&histw[g >> 1], (g & 1) ? 65536u : 1u);
  }
  __syncthreads();   // [10] all xs/ys reads + hist atomics done

  // ---- write ecdf overlay (over dead ys region); wave 0 scans hist->lut2 ----
#pragma unroll
  for (int s = 0; s < N3 / T; ++s) ecdf[tid + s * T] = ev[s];
  if (tid < 64) {
    int base5 = 5 * tid;
    int h[5]; int lsum = 0;
#pragma unroll
    for (int r = 0; r < 5; ++r) {
      int b = base5 + r;
      h[r] = (b < 258) ? (int)hist[b] : 0;
      lsum += h[r];
    }
    int pg = lsum;
#pragma unroll
    for (int off = 1; off < 64; off <<= 1) {
      int v = __shfl_up(pg, off);
      if (lane >= off) pg += v;
    }
    int run = pg - lsum;                     // exclusive prefix of this lane
#pragma unroll
    for (int r = 0; r < 5; ++r) {
      run += h[r];                           // inclusive through bin base5+r
      int m = base5 + r;
      if (m <= 256) lut2[m] = (u16)run;      // = #{ecdf < vgrid(m)} (sorted ecdf)
    }
  }
  __syncthreads();   // [11] ecdf + lut2 visible

  // ---- stage 2: inverse-CDF embedding + circular cost partial sum ----
  float alpha = s_alpha;
  float accf = 0.f;
#pragma unroll
  for (int s = 0; s < NG / T; ++s) {
    int kq = tid + s * T;
    float xg = (float)kq / 1024.0f;
    float q2 = xg - alpha;
    int k2 = (int)floorf((q2 + 1.0f) * (256.0f / 3.0f));
    k2 = k2 < 0 ? 0 : (k2 > 255 ? 255 : k2);
    int blo = k2 > 0 ? k2 - 1 : 0;           // widen +-1: immune to fp rounding of k2
    int bhi = k2 < 254 ? k2 + 2 : 256;
    int lo = lower_bound_f(ecdf, (int)lut2[blo], (int)lut2[bhi], q2);
    int ind = lo - 1;
    ind = ind < 0 ? 0 : (ind > N3 - 2 ? N3 - 2 : ind);
    float e0 = ecdf[ind], e1 = ecdf[ind + 1];
    float y0 = -1.0f + (3.0f * (float)ind) / 3071.0f;
    float y1 = -1.0f + (3.0f * (float)(ind + 1)) / 3071.0f;
    float slope = (y1 - y0) * __builtin_amdgcn_rcpf(FEPS + (e1 - e0));
    float emb = y0 + slope * (q2 - e0) - xg;
    float a = fabsf(emb);
    float m = fminf(a, 1.0f - a);
    accf += m * m;
  }
#pragma unroll
  for (int off = 32; off > 0; off >>= 1) accf += __shfl_down(accf, off);
  if (lane == 0) redA[wave] = accf;
  __syncthreads();   // [12]
  if (tid == 0) {
    float s = 0.f;
#pragma unroll
    for (int i = 0; i < NW; ++i) s += redA[i];
    rowsum[row] = s;
  }
}

__global__ __launch_bounds__(256) void lcot_final(const float* __restrict__ rowsum,
                                                  float* __restrict__ out) {
  __shared__ float red[4];
  int t = threadIdx.x;
  float s = 0.f;
  for (int i = t; i < L; i += 256) s += rowsum[i];
#pragma unroll
  for (int off = 32; off > 0; off >>= 1) s += __shfl_down(s, off);
  if ((t & 63) == 0) red[t >> 6] = s;
  __syncthreads();
  if (t == 0) {
    float tot = red[0] + red[1] + red[2] + red[3];
    out[0] = sqrtf(tot / (float)L + 1e-8f);
  }
}

extern "C" void kernel_launch(void* const* d_in, const int* in_sizes, int n_in,
                              void* d_out, int out_size, void* d_ws, size_t ws_size,
                              hipStream_t stream) {
  const float* X = (const float*)d_in[0];
  const float* W = (const float*)d_in[1];
  float* rowsum = (float*)d_ws;  // 2048 floats
  // 32768 (pairs/xs/ys, ecdf overlays ys) + 4104 (cnt) + 516 (lut2+pad) + 516 (hist)
  size_t shbytes = 37904;  // -> 4 blocks/CU, 32 waves/CU
  hipLaunchKernelGGL(lcot_rows, dim3(L), dim3(T), shbytes, stream, X, W, rowsum);
  hipLaunchKernelGGL(lcot_final, dim3(1), dim3(256), 0, stream,
                     (const float*)rowsum, (float*)d_out);
}

// Round 10
// 179.035 us; speedup vs baseline: 1.0902x; 1.0902x over previous
//
#include <hip/hip_runtime.h>
#include <math.h>

#define L    2048
#define NCOL 4096
#define NG   1024
#define N3   3072
#define T    512
#define NW   8            // waves per block
#define EPT  8            // NCOL / T
#define NB   2048         // buckets (exact: floor(x*2048), power-of-two mult)
#define FEPS 1.1920929e-07f

typedef unsigned long long u64;
typedef unsigned short u16;
typedef unsigned int u32;

__device__ __forceinline__ int lower_bound_f(const float* a, int lo, int hi, float v) {
  // exact replica of numpy's npy_binsearch (side='left') on [lo,hi)
  while (lo < hi) {
    int mid = (lo + hi) >> 1;
    if (a[mid] < v) lo = mid + 1; else hi = mid;
  }
  return lo;
}

__device__ __forceinline__ int bucket_of_bits(unsigned xb) {
  float f = __uint_as_float(xb);
  int b = (int)(f * (float)NB);          // exact: mult by 2^11
  return b > NB - 1 ? NB - 1 : b;
}

// LDS layout (37,392 B dynamic -> 4 blocks/CU, 32 waves/CU):
//   [0,32768)      pairs u64[4096]; aliased later: xs f32[4096] @0, ys f32[4096] @16384
//   [16384,28672)  ecdf f32[3072] overlays ys AFTER stage-1 (ys dead by then)
//   [32768,36872)  cnt u16[2050] (packed u32 words for atomics), padded
//   [36872,37392)  lut2 u16[257]
__global__ __launch_bounds__(T, 8) void lcot_rows(const float* __restrict__ X,
                                                  const float* __restrict__ W,
                                                  float* __restrict__ rowsum) {
  extern __shared__ char smem[];
  u64*   pairs = (u64*)smem;
  float* xs    = (float*)smem;
  float* ys    = (float*)(smem + 16384);
  float* ecdf  = (float*)(smem + 16384);          // overlay, used after stage-1
  u16*   cnt16 = (u16*)(smem + 32768);
  u32*   cntw  = (u32*)(smem + 32768);
  u16*   lut2  = (u16*)(smem + 36872);

  __shared__ float redA[NW], redB[NW], fwt[NW];
  __shared__ int   iwt[NW];
  __shared__ float s_alpha;

  const int tid  = threadIdx.x;
  const int lane = tid & 63;
  const int wave = tid >> 6;
  const int row  = blockIdx.x;
  const float* xr = X + (size_t)row * NCOL;
  const float* wr = W + (size_t)row * NCOL;

  // ---- zero packed histogram (1025 u32 words incl. sentinel word) ----
  for (int i = tid; i < 1025; i += T) cntw[i] = 0u;

  // ---- load 8 consecutive elems, pack stable keys, alpha partials ----
  u64 key[EPT];
  float sxw = 0.f, sw = 0.f;
  const float4* xr4 = (const float4*)xr;
  const float4* wr4 = (const float4*)wr;
#pragma unroll
  for (int c = 0; c < 2; ++c) {
    float4 xv = xr4[tid * 2 + c];
    float4 ww = wr4[tid * 2 + c];
    sxw += xv.x * ww.x + xv.y * ww.y + xv.z * ww.z + xv.w * ww.w;
    sw  += ww.x + ww.y + ww.z + ww.w;
    int b = 8 * tid + 4 * c;
    key[4*c+0] = ((u64)__float_as_uint(xv.x) << 32) | (unsigned)(b + 0);
    key[4*c+1] = ((u64)__float_as_uint(xv.y) << 32) | (unsigned)(b + 1);
    key[4*c+2] = ((u64)__float_as_uint(xv.z) << 32) | (unsigned)(b + 2);
    key[4*c+3] = ((u64)__float_as_uint(xv.w) << 32) | (unsigned)(b + 3);
  }
#pragma unroll
  for (int off = 32; off > 0; off >>= 1) {
    sxw += __shfl_down(sxw, off);
    sw  += __shfl_down(sw, off);
  }
  if (lane == 0) { redA[wave] = sxw; redB[wave] = sw; }
  __syncthreads();   // [1] zeroed cnt + redA/redB visible

  // ---- histogram on packed u16 fields: ord from atomic return ----
  int ord[EPT];
#pragma unroll
  for (int e = 0; e < EPT; ++e) {
    int b = bucket_of_bits((unsigned)(key[e] >> 32));
    u32 inc = (b & 1) ? 65536u : 1u;
    u32 ret = atomicAdd(&cntw[b >> 1], inc);
    ord[e] = (b & 1) ? (int)(ret >> 16) : (int)(ret & 0xffffu);
  }
  __syncthreads();   // [2] all atomics done
  if (tid == 0) {
    float a = 0.f, b = 0.f;
#pragma unroll
    for (int i = 0; i < NW; ++i) { a += redA[i]; b += redB[i]; }
    s_alpha = a / b - 0.5f;
  }

  // ---- exclusive scan of 2048 u16 counts -> bases (packed, in place) ----
  u32 cv0 = cntw[2 * tid], cv1 = cntw[2 * tid + 1];
  int c0 = (int)(cv0 & 0xffffu), c1 = (int)(cv0 >> 16);
  int c2 = (int)(cv1 & 0xffffu), c3 = (int)(cv1 >> 16);
  int runi = c0 + c1 + c2 + c3;
  int toti = runi, prei = runi;
#pragma unroll
  for (int off = 1; off < 64; off <<= 1) {
    int v = __shfl_up(prei, off);
    if (lane >= off) prei += v;
  }
  if (lane == 63) iwt[wave] = prei;
  __syncthreads();   // [3] iwt visible (each thread only rewrites its own words)
  int wpre = 0;
#pragma unroll
  for (int w2 = 0; w2 < NW; ++w2) wpre += (w2 < wave) ? iwt[w2] : 0;
  int acc = wpre + prei - toti;
  {
    int b0 = acc; acc += c0;
    int b1 = acc; acc += c1;
    int b2 = acc; acc += c2;
    int b3 = acc; acc += c3;
    cntw[2 * tid]     = (u32)b0 | ((u32)b1 << 16);
    cntw[2 * tid + 1] = (u32)b2 | ((u32)b3 << 16);
  }
  if (tid == T - 1) cnt16[NB] = (u16)acc;   // sentinel = 4096
  __syncthreads();   // [4] bases visible

  // ---- scatter keys into bucket slots (arrival order) ----
#pragma unroll
  for (int e = 0; e < EPT; ++e) {
    int b = bucket_of_bits((unsigned)(key[e] >> 32));
    pairs[(int)cnt16[b] + ord[e]] = key[e];
  }
  __syncthreads();   // [5]

  // ---- per-bucket insertion sort in LDS (4 buckets/thread, disjoint slots) ----
  // strict u64 order (xbits, idx) == exact stable argsort
#pragma unroll
  for (int bb = 0; bb < 4; ++bb) {
    int b  = 4 * tid + bb;
    int lo = (int)cnt16[b], hi = (int)cnt16[b + 1];
    for (int i = lo + 1; i < hi; ++i) {
      u64 v = pairs[i];
      int j = i - 1;
      while (j >= lo && pairs[j] > v) { pairs[j + 1] = pairs[j]; --j; }
      pairs[j + 1] = v;
    }
  }
  __syncthreads();   // [6] pairs fully sorted

  // ---- stage own 8 sorted slots to registers; gather w by index ----
  u64 q[EPT];
  {
    const ulonglong2* pr2 = (const ulonglong2*)pairs + 4 * tid;
#pragma unroll
    for (int c = 0; c < 4; ++c) { ulonglong2 v = pr2[c]; q[2*c] = v.x; q[2*c+1] = v.y; }
  }
  float wg[EPT];
#pragma unroll
  for (int e = 0; e < EPT; ++e) wg[e] = wr[(u32)(q[e] & 0xffffffffu)];
  __syncthreads();   // [7] all pairs reads done before aliasing xs/ys writes

  // ---- write sorted xs (vector); cumsum weights in registers ----
  {
    float4 xa0, xa1;
    xa0.x = __uint_as_float((u32)(q[0] >> 32));
    xa0.y = __uint_as_float((u32)(q[1] >> 32));
    xa0.z = __uint_as_float((u32)(q[2] >> 32));
    xa0.w = __uint_as_float((u32)(q[3] >> 32));
    xa1.x = __uint_as_float((u32)(q[4] >> 32));
    xa1.y = __uint_as_float((u32)(q[5] >> 32));
    xa1.z = __uint_as_float((u32)(q[6] >> 32));
    xa1.w = __uint_as_float((u32)(q[7] >> 32));
    ((float4*)xs)[2 * tid]     = xa0;
    ((float4*)xs)[2 * tid + 1] = xa1;
  }
  float lw[EPT];
  float runf = 0.f;
#pragma unroll
  for (int c = 0; c < EPT; ++c) { runf += wg[c]; lw[c] = runf; }
  float totf = runf, pref = runf;
#pragma unroll
  for (int off = 1; off < 64; off <<= 1) {
    float v = __shfl_up(pref, off);
    if (lane >= off) pref += v;
  }
  if (lane == 63) fwt[wave] = pref;
  __syncthreads();   // [8] fwt visible
  float wpf = 0.f;
#pragma unroll
  for (int w2 = 0; w2 < NW; ++w2) wpf += (w2 < wave) ? fwt[w2] : 0.f;
  float basef = wpf + pref - totf;
  {
    ((float4*)ys)[2 * tid]     = make_float4(basef + lw[0], basef + lw[1],
                                             basef + lw[2], basef + lw[3]);
    ((float4*)ys)[2 * tid + 1] = make_float4(basef + lw[4], basef + lw[5],
                                             basef + lw[6], basef + lw[7]);
  }
  __syncthreads();   // [9] xs + CDF visible

  // ---- stage 1: ecdf values into REGISTERS (bucket bases = exact brackets) ----
  float ev[N3 / T];
#pragma unroll
  for (int s = 0; s < N3 / T; ++s) {
    int j = tid + s * T;
    float xnew = -1.0f + (3.0f * (float)j) / 3071.0f;
    float ix = floorf(xnew);
    float rest = xnew - ix;                  // in [0,1)
    int k = (int)(rest * (float)NB);         // exact
    k = k > NB - 1 ? NB - 1 : k;
    int lo = lower_bound_f(xs, (int)cnt16[k], (int)cnt16[k + 1], rest);
    int ind = lo - 1;
    ind = ind < 0 ? 0 : (ind > NCOL - 2 ? NCOL - 2 : ind);
    float x0 = xs[ind], x1v = xs[ind + 1];
    float y0 = ys[ind], y1v = ys[ind + 1];
    float slope = (y1v - y0) * __builtin_amdgcn_rcpf(FEPS + (x1v - x0));
    ev[s] = ix + (y0 + slope * (rest - x0));
  }
  __syncthreads();   // [10] all xs/ys reads done -> ys region reusable

  // ---- write ecdf overlay (over dead ys region) ----
#pragma unroll
  for (int s = 0; s < N3 / T; ++s) ecdf[tid + s * T] = ev[s];
  __syncthreads();   // [11]

  // ---- stage-2 value LUT over ecdf range [-1,2): 257 brackets ----
  if (tid < 257) {
    float v = -1.0f + 3.0f * (float)tid * (1.0f / 256.0f);
    lut2[tid] = (u16)lower_bound_f(ecdf, 0, N3, v);
  }
  __syncthreads();   // [12]

  // ---- stage 2: inverse-CDF embedding + circular cost partial sum ----
  float alpha = s_alpha;
  float accf = 0.f;
#pragma unroll
  for (int s = 0; s < NG / T; ++s) {
    int kq = tid + s * T;
    float xg = (float)kq / 1024.0f;
    float q2 = xg - alpha;
    int k2 = (int)floorf((q2 + 1.0f) * (256.0f / 3.0f));
    k2 = k2 < 0 ? 0 : (k2 > 255 ? 255 : k2);
    int blo = k2 > 0 ? k2 - 1 : 0;           // widen +-1: immune to fp rounding of k2
    int bhi = k2 < 254 ? k2 + 2 : 256;
    int lo = lower_bound_f(ecdf, (int)lut2[blo], (int)lut2[bhi], q2);
    int ind = lo - 1;
    ind = ind < 0 ? 0 : (ind > N3 - 2 ? N3 - 2 : ind);
    float e0 = ecdf[ind], e1 = ecdf[ind + 1];
    float y0 = -1.0f + (3.0f * (float)ind) / 3071.0f;
    float y1 = -1.0f + (3.0f * (float)(ind + 1)) / 3071.0f;
    float slope = (y1 - y0) * __builtin_amdgcn_rcpf(FEPS + (e1 - e0));
    float emb = y0 + slope * (q2 - e0) - xg;
    float a = fabsf(emb);
    float m = fminf(a, 1.0f - a);
    accf += m * m;
  }
#pragma unroll
  for (int off = 32; off > 0; off >>= 1) accf += __shfl_down(accf, off);
  if (lane == 0) redA[wave] = accf;
  __syncthreads();   // [13]
  if (tid == 0) {
    float s = 0.f;
#pragma unroll
    for (int i = 0; i < NW; ++i) s += redA[i];
    rowsum[row] = s;
  }
}

__global__ __launch_bounds__(256) void lcot_final(const float* __restrict__ rowsum,
                                                  float* __restrict__ out) {
  __shared__ float red[4];
  int t = threadIdx.x;
  float s = 0.f;
  for (int i = t; i < L; i += 256) s += rowsum[i];
#pragma unroll
  for (int off = 32; off > 0; off >>= 1) s += __shfl_down(s, off);
  if ((t & 63) == 0) red[t >> 6] = s;
  __syncthreads();
  if (t == 0) {
    float tot = red[0] + red[1] + red[2] + red[3];
    out[0] = sqrtf(tot / (float)L + 1e-8f);
  }
}

extern "C" void kernel_launch(void* const* d_in, const int* in_sizes, int n_in,
                              void* d_out, int out_size, void* d_ws, size_t ws_size,
                              hipStream_t stream) {
  const float* X = (const float*)d_in[0];
  const float* W = (const float*)d_in[1];
  float* rowsum = (float*)d_ws;  // 2048 floats
  // 32768 (pairs/xs/ys, ecdf overlays ys) + 4104 (u16 cnt) + 520 (lut2) = 37,392 B
  size_t shbytes = 32768 + 4104 + 520;
  hipLaunchKernelGGL(lcot_rows, dim3(L), dim3(T), shbytes, stream, X, W, rowsum);
  hipLaunchKernelGGL(lcot_final, dim3(1), dim3(256), 0, stream,
                     (const float*)rowsum, (float*)d_out);
}